// Round 1
// baseline (292.991 us; speedup 1.0000x reference)
//
#include <hip/hip_runtime.h>
#include <math.h>

typedef unsigned short u16;
typedef unsigned int   u32;
typedef __attribute__((ext_vector_type(4))) float f32x4;
typedef __attribute__((ext_vector_type(8))) short s16x8;
typedef __attribute__((ext_vector_type(4))) unsigned short u16x4;

#define B_N   2
#define S_N   2048
#define HID_N 1024
#define H_N   8
#define HKV_N 2
#define D_N   256
#define QKVW  5120   // qkv_raw row width: 2048 q | 2048 gate | 512 k | 512 v

__device__ __forceinline__ u16 f2bf(float f) {
  union { float f; u32 u; } x; x.f = f;
  u32 r = x.u + 0x7FFFu + ((x.u >> 16) & 1u);
  return (u16)(r >> 16);
}
__device__ __forceinline__ float bf2f(u16 u) {
  union { u32 u; float f; } x; x.u = ((u32)u) << 16; return x.f;
}
__device__ __forceinline__ void gload_lds16(const u16* g, u16* l) {
  __builtin_amdgcn_global_load_lds((const __attribute__((address_space(1))) u32*)g,
                                   (__attribute__((address_space(3))) u32*)l, 16, 0, 0);
}

// ---------------- fp32 -> bf16 cast ----------------
__global__ __launch_bounds__(256)
void cast_bf16_kernel(const float* __restrict__ src, u16* __restrict__ dst, int n4) {
  int i = blockIdx.x * blockDim.x + threadIdx.x;
  int stride = gridDim.x * blockDim.x;
  for (; i < n4; i += stride) {
    float4 v = reinterpret_cast<const float4*>(src)[i];
    u16x4 o;
    o.x = f2bf(v.x); o.y = f2bf(v.y); o.z = f2bf(v.z); o.w = f2bf(v.w);
    reinterpret_cast<u16x4*>(dst)[i] = o;
  }
}

// ---------------- RoPE trig table (fp64 on device, tiny) ----------------
__global__ __launch_bounds__(256)
void trig_kernel(const int* __restrict__ pos, float* __restrict__ ct, float* __restrict__ st) {
  int i = blockIdx.x * blockDim.x + threadIdx.x;
  if (i >= S_N * 32) return;
  int s = i >> 5, j = i & 31;
  double inv = exp(-(double)j * (log(1.0e7) / 32.0));
  double ang = (double)pos[s] * inv;
  ct[i] = (float)cos(ang);
  st[i] = (float)sin(ang);
}

// ---------------- bf16 GEMM: C[M,N] = A[M,K] @ Bw[N,K]^T ----------------
// 128x128 tile, BK=32, 4 waves (2x2), 16x16x32 MFMA, global_load_lds dbuf.
template <int OUT_BF16>
__global__ __launch_bounds__(256, 2)
void gemm_bt_kernel(const u16* __restrict__ A, const u16* __restrict__ Bw,
                    void* __restrict__ Cout, int M, int N, int K) {
  const int nbn = N >> 7;
  const int bm = blockIdx.x / nbn;
  const int bn = blockIdx.x % nbn;
  const int tid = threadIdx.x;
  const int lane = tid & 63;
  const int wr = tid >> 7;
  const int wc = (tid >> 6) & 1;
  __shared__ u16 sA[2][128 * 32];
  __shared__ u16 sB[2][128 * 32];
  f32x4 acc[4][4] = {};
  const u16* Ab = A + (size_t)(bm << 7) * K;
  const u16* Bb = Bw + (size_t)(bn << 7) * K;
  const int r_st = tid >> 2;
  const int c_st = (tid & 3) * 8;
  const int nkt = K >> 5;

  auto stage = [&](int buf, int kt) {
    const int k0 = kt << 5;
    gload_lds16(Ab + (size_t)r_st * K + k0 + c_st,        &sA[buf][tid * 8]);
    gload_lds16(Ab + (size_t)(r_st + 64) * K + k0 + c_st, &sA[buf][2048 + tid * 8]);
    gload_lds16(Bb + (size_t)r_st * K + k0 + c_st,        &sB[buf][tid * 8]);
    gload_lds16(Bb + (size_t)(r_st + 64) * K + k0 + c_st, &sB[buf][2048 + tid * 8]);
  };

  stage(0, 0);
  int cur = 0;
  const int ra = (wr << 6) + (lane & 15);
  const int rb = (wc << 6) + (lane & 15);
  const int ks = (lane >> 4) << 3;
  for (int kt = 0; kt < nkt; ++kt) {
    asm volatile("s_waitcnt vmcnt(0)" ::: "memory");
    __syncthreads();
    if (kt + 1 < nkt) stage(cur ^ 1, kt + 1);
    const u16* sa = sA[cur];
    const u16* sb = sB[cur];
    s16x8 af[4], bfr[4];
#pragma unroll
    for (int m = 0; m < 4; ++m) af[m] = *reinterpret_cast<const s16x8*>(sa + (ra + m * 16) * 32 + ks);
#pragma unroll
    for (int n = 0; n < 4; ++n) bfr[n] = *reinterpret_cast<const s16x8*>(sb + (rb + n * 16) * 32 + ks);
#pragma unroll
    for (int m = 0; m < 4; ++m)
#pragma unroll
      for (int n = 0; n < 4; ++n)
        acc[m][n] = __builtin_amdgcn_mfma_f32_16x16x32_bf16(af[m], bfr[n], acc[m][n], 0, 0, 0);
    __syncthreads();
    cur ^= 1;
  }
  const int row0 = (bm << 7) + (wr << 6) + ((lane >> 4) << 2);
  const int col0 = (bn << 7) + (wc << 6) + (lane & 15);
#pragma unroll
  for (int m = 0; m < 4; ++m)
#pragma unroll
    for (int n = 0; n < 4; ++n)
#pragma unroll
      for (int j = 0; j < 4; ++j) {
        size_t idx = (size_t)(row0 + m * 16 + j) * N + col0 + n * 16;
        if (OUT_BF16) ((u16*)Cout)[idx] = f2bf(acc[m][n][j]);
        else          ((float*)Cout)[idx] = acc[m][n][j];
      }
}

// ---------------- RMSNorm + RoPE for q and k ----------------
// one wave per (b,s,head) row of 256; q rows first (B*S*H), then k rows (B*S*HKV)
__global__ __launch_bounds__(256)
void normrope_kernel(const u16* __restrict__ qkv, const float* __restrict__ qw,
                     const float* __restrict__ kw, const float* __restrict__ ct,
                     const float* __restrict__ st, u16* __restrict__ q_r,
                     u16* __restrict__ k_r) {
  const int lane = threadIdx.x & 63;
  const int row = blockIdx.x * 4 + (threadIdx.x >> 6);
  const int nq = B_N * S_N * H_N;
  const u16* src; u16* dst; const float* w;
  int s;
  if (row < nq) {
    int h = row & 7; int bs = row >> 3; s = bs & (S_N - 1); int b = bs >> 11;
    src = qkv + (size_t)(b * S_N + s) * QKVW + h * 256;
    dst = q_r + ((size_t)(b * H_N + h) * S_N + s) * 256;
    w = qw;
  } else {
    int r2 = row - nq;
    int h = r2 & 1; int bs = r2 >> 1; s = bs & (S_N - 1); int b = bs >> 11;
    src = qkv + (size_t)(b * S_N + s) * QKVW + 4096 + h * 256;
    dst = k_r + ((size_t)(b * HKV_N + h) * S_N + s) * 256;
    w = kw;
  }
  u16x4 xv = *reinterpret_cast<const u16x4*>(src + lane * 4);
  float x0 = bf2f(xv.x), x1 = bf2f(xv.y), x2 = bf2f(xv.z), x3 = bf2f(xv.w);
  float ss = x0 * x0 + x1 * x1 + x2 * x2 + x3 * x3;
#pragma unroll
  for (int off = 1; off < 64; off <<= 1) ss += __shfl_xor(ss, off);
  float rinv = rsqrtf(ss * (1.0f / 256.0f) + 1e-6f);
  float4 wv = *reinterpret_cast<const float4*>(w + lane * 4);
  float y[4] = { x0 * rinv * wv.x, x1 * rinv * wv.y, x2 * rinv * wv.z, x3 * rinv * wv.w };
  float p[4];
  p[0] = __shfl_xor(y[0], 8);
  p[1] = __shfl_xor(y[1], 8);
  p[2] = __shfl_xor(y[2], 8);
  p[3] = __shfl_xor(y[3], 8);
  if (lane < 16) {
    const float sgn = (lane < 8) ? -1.0f : 1.0f;
    const int jb = (lane * 4) & 31;
#pragma unroll
    for (int e = 0; e < 4; ++e) {
      float c = ct[(size_t)s * 32 + jb + e];
      float sn = st[(size_t)s * 32 + jb + e];
      y[e] = y[e] * c + sgn * p[e] * sn;
    }
  }
  u16x4 ov;
  ov.x = f2bf(y[0]); ov.y = f2bf(y[1]); ov.z = f2bf(y[2]); ov.w = f2bf(y[3]);
  *reinterpret_cast<u16x4*>(dst + lane * 4) = ov;
}

// ---------------- V transpose: qkv_raw v-part (b,s,kvh,d) -> vt[(b,kvh,d), s] ----------------
__global__ __launch_bounds__(256)
void vtrans_kernel(const u16* __restrict__ qkv, u16* __restrict__ vt) {
  const int bid = blockIdx.x;            // 4*32*4 = 512
  const int dt = bid & 3;
  const int stile = (bid >> 2) & 31;
  const int bh = bid >> 7;               // b*HKV+kvh
  const int b = bh >> 1, kvh = bh & 1;
  __shared__ u16 tile[64][68];
  const int t = threadIdx.x;
  const u16* src = qkv + (size_t)(b * S_N + stile * 64) * QKVW + 4608 + kvh * 256 + dt * 64;
#pragma unroll
  for (int i = 0; i < 2; ++i) {
    int sl = i * 32 + (t >> 3);
    int d8 = (t & 7) * 8;
    s16x8 v = *reinterpret_cast<const s16x8*>(src + (size_t)sl * QKVW + d8);
    u16x4 lo = { (u16)v[0], (u16)v[1], (u16)v[2], (u16)v[3] };
    u16x4 hi = { (u16)v[4], (u16)v[5], (u16)v[6], (u16)v[7] };
    *reinterpret_cast<u16x4*>(&tile[sl][d8]) = lo;
    *reinterpret_cast<u16x4*>(&tile[sl][d8 + 4]) = hi;
  }
  __syncthreads();
#pragma unroll
  for (int i = 0; i < 2; ++i) {
    int dl = i * 32 + (t >> 3);
    int s8 = (t & 7) * 8;
    u16 tmp[8];
#pragma unroll
    for (int e = 0; e < 8; ++e) tmp[e] = tile[s8 + e][dl];
    u16x4 lo = { tmp[0], tmp[1], tmp[2], tmp[3] };
    u16x4 hi = { tmp[4], tmp[5], tmp[6], tmp[7] };
    u16* dstp = vt + ((size_t)(bh * 256 + dt * 64 + dl)) * S_N + stile * 64 + s8;
    *reinterpret_cast<u16x4*>(dstp) = lo;
    *reinterpret_cast<u16x4*>(dstp + 4) = hi;
  }
}

// ---------------- flash attention + silu gating ----------------
// block = 4 waves; wave handles 16 q rows; KV tile = 32; D = 256.
__global__ __launch_bounds__(256, 2)
void attn_kernel(const u16* __restrict__ q_r, const u16* __restrict__ k_r,
                 const u16* __restrict__ vt, const u16* __restrict__ qkv,
                 u16* __restrict__ act) {
  const int bid = blockIdx.x;            // B*H*(S/64) = 512
  const int qt = bid & 31;
  const int h = (bid >> 5) & 7;
  const int b = bid >> 8;
  const int kvh = h >> 2;                // G = 4
  const int tid = threadIdx.x;
  const int lane = tid & 63;
  const int wv = tid >> 6;
  const int l15 = lane & 15;
  const int l4 = lane >> 4;

  __shared__ u16 sK[2][32 * 256];        // [kv][d], XOR-swizzled 16B slots
  __shared__ u16 sVt[2][256 * 32];       // [d][kv], XOR-swizzled
  __shared__ u16 sP[4][16 * 32];         // per-wave P tile, swizzled

  const int q0 = qt * 64 + wv * 16;
  const u16* qb = q_r + ((size_t)(b * H_N + h) * S_N + q0) * 256;
  s16x8 qf[8];
#pragma unroll
  for (int kk = 0; kk < 8; ++kk)
    qf[kk] = *reinterpret_cast<const s16x8*>(qb + (size_t)l15 * 256 + kk * 32 + l4 * 8);

  f32x4 oacc[16] = {};
  float mrow[4] = { -1e30f, -1e30f, -1e30f, -1e30f };
  float lrow[4] = { 0.f, 0.f, 0.f, 0.f };

  const u16* kbase = k_r + ((size_t)(b * HKV_N + kvh) * S_N) * 256;
  const u16* vbase = vt + ((size_t)(b * HKV_N + kvh) * 256) * S_N;

  const int krow = tid >> 5;                                 // 0..7
  const int kcs = ((tid & 31) ^ krow) << 3;                  // pre-swizzled global col (elems)
  const int vrow = tid >> 2;                                 // 0..63
  const int vsw = ((tid & 3) ^ ((vrow >> 1) & 3)) << 3;

  auto stageKV = [&](int buf, int step) {
    const int kv0 = step << 5;
#pragma unroll
    for (int i = 0; i < 4; ++i)
      gload_lds16(kbase + (size_t)(kv0 + i * 8 + krow) * 256 + kcs, &sK[buf][i * 2048 + tid * 8]);
#pragma unroll
    for (int i = 0; i < 4; ++i)
      gload_lds16(vbase + (size_t)(i * 64 + vrow) * S_N + kv0 + vsw, &sVt[buf][i * 2048 + tid * 8]);
  };

  stageKV(0, 0);
  int cur = 0;
  const float scale = 0.0625f;  // 1/sqrt(256)
  for (int step = 0; step < 64; ++step) {
    asm volatile("s_waitcnt vmcnt(0)" ::: "memory");
    __syncthreads();
    if (step + 1 < 64) stageKV(cur ^ 1, step + 1);
    const u16* ktile = sK[cur];
    const u16* vtile = sVt[cur];
    f32x4 sacc0 = {}, sacc1 = {};
#pragma unroll
    for (int kk = 0; kk < 8; ++kk) {
      const int slot = kk * 4 + l4;
      {
        const int row = l15;
        s16x8 kf = *reinterpret_cast<const s16x8*>(ktile + row * 256 + ((slot ^ (row & 7)) << 3));
        sacc0 = __builtin_amdgcn_mfma_f32_16x16x32_bf16(qf[kk], kf, sacc0, 0, 0, 0);
      }
      {
        const int row = 16 + l15;
        s16x8 kf = *reinterpret_cast<const s16x8*>(ktile + row * 256 + ((slot ^ (row & 7)) << 3));
        sacc1 = __builtin_amdgcn_mfma_f32_16x16x32_bf16(qf[kk], kf, sacc1, 0, 0, 0);
      }
    }
    // online softmax (rows live in 16-lane groups; reg j = row)
    float alpha[4], p0[4], p1[4];
#pragma unroll
    for (int j = 0; j < 4; ++j) {
      float v = fmaxf(sacc0[j], sacc1[j]);
      v = fmaxf(v, __shfl_xor(v, 1));
      v = fmaxf(v, __shfl_xor(v, 2));
      v = fmaxf(v, __shfl_xor(v, 4));
      v = fmaxf(v, __shfl_xor(v, 8));
      float mnew = fmaxf(mrow[j], v * scale);
      alpha[j] = __expf(mrow[j] - mnew);
      mrow[j] = mnew;
      p0[j] = __expf(sacc0[j] * scale - mnew);
      p1[j] = __expf(sacc1[j] * scale - mnew);
      float rsum = p0[j] + p1[j];
      rsum += __shfl_xor(rsum, 1);
      rsum += __shfl_xor(rsum, 2);
      rsum += __shfl_xor(rsum, 4);
      rsum += __shfl_xor(rsum, 8);
      lrow[j] = lrow[j] * alpha[j] + rsum;
    }
#pragma unroll
    for (int nf = 0; nf < 16; ++nf) {
      oacc[nf][0] *= alpha[0]; oacc[nf][1] *= alpha[1];
      oacc[nf][2] *= alpha[2]; oacc[nf][3] *= alpha[3];
    }
    // P -> bf16 -> per-wave LDS (swizzled), then read as MFMA A-frag
    u16* pl = &sP[wv][0];
#pragma unroll
    for (int j = 0; j < 4; ++j) {
      const int row = l4 * 4 + j;
      const int xr = (row >> 1) & 3;
      {
        const int col = l15;
        pl[row * 32 + ((((col >> 3) ^ xr) << 3) | (col & 7))] = f2bf(p0[j]);
      }
      {
        const int col = 16 + l15;
        pl[row * 32 + ((((col >> 3) ^ xr) << 3) | (col & 7))] = f2bf(p1[j]);
      }
    }
    asm volatile("s_waitcnt lgkmcnt(0)" ::: "memory");
    __builtin_amdgcn_sched_barrier(0);
    {
      const int prow = l15;
      const int pxr = (prow >> 1) & 3;
      s16x8 paf = *reinterpret_cast<const s16x8*>(pl + prow * 32 + ((l4 ^ pxr) << 3));
#pragma unroll
      for (int nf = 0; nf < 16; ++nf) {
        const int d = nf * 16 + l15;
        s16x8 vf = *reinterpret_cast<const s16x8*>(vtile + d * 32 + ((l4 ^ ((d >> 1) & 3)) << 3));
        oacc[nf] = __builtin_amdgcn_mfma_f32_16x16x32_bf16(paf, vf, oacc[nf], 0, 0, 0);
      }
    }
    __syncthreads();
    cur ^= 1;
  }
  // epilogue: O/l, silu(gate) gating, write activation for final GEMM
  float invl[4];
#pragma unroll
  for (int j = 0; j < 4; ++j) invl[j] = 1.0f / lrow[j];
#pragma unroll
  for (int nf = 0; nf < 16; ++nf) {
#pragma unroll
    for (int j = 0; j < 4; ++j) {
      const int srow = q0 + l4 * 4 + j;
      const int d = nf * 16 + l15;
      float o = oacc[nf][j] * invl[j];
      float g = bf2f(qkv[(size_t)(b * S_N + srow) * QKVW + 2048 + h * 256 + d]);
      float sg = g / (1.0f + __expf(-g));
      act[(size_t)(b * S_N + srow) * 2048 + h * 256 + d] = f2bf(o * sg);
    }
  }
}

extern "C" void kernel_launch(void* const* d_in, const int* in_sizes, int n_in,
                              void* d_out, int out_size, void* d_ws, size_t ws_size,
                              hipStream_t stream) {
  const float* hs  = (const float*)d_in[0];
  const int*   pos = (const int*)d_in[1];
  const float* Wq  = (const float*)d_in[2];
  const float* Wk  = (const float*)d_in[3];
  const float* Wv  = (const float*)d_in[4];
  const float* Wo  = (const float*)d_in[5];
  const float* qw  = (const float*)d_in[6];
  const float* kw  = (const float*)d_in[7];
  float* out = (float*)d_out;

  char* w8 = (char*)d_ws;
  u16* hs_bf   = (u16*)(w8);                    // 8,388,608 B
  u16* wqkv_bf = (u16*)(w8 + 8388608);          // 10,485,760
  u16* wo_bf   = (u16*)(w8 + 18874368);         // 4,194,304
  u16* qkv_raw = (u16*)(w8 + 23068672);         // 41,943,040
  u16* q_r     = (u16*)(w8 + 65011712);         // 16,777,216
  u16* k_r     = (u16*)(w8 + 81788928);         // 4,194,304
  u16* vt      = (u16*)(w8 + 85983232);         // 4,194,304
  u16* act     = (u16*)(w8 + 90177536);         // 16,777,216
  float* cost  = (float*)(w8 + 106954752);      // 262,144
  float* sint  = (float*)(w8 + 107216896);      // 262,144  -> total 107,479,040

  auto cast_launch = [&](const float* src, u16* dst, int n) {
    int n4 = n >> 2;
    int blocks = (n4 + 255) / 256;
    if (blocks > 2048) blocks = 2048;
    cast_bf16_kernel<<<blocks, 256, 0, stream>>>(src, dst, n4);
  };
  cast_launch(hs, hs_bf, B_N * S_N * HID_N);
  cast_launch(Wq, wqkv_bf, 4096 * 1024);
  cast_launch(Wk, wqkv_bf + 4194304, 512 * 1024);
  cast_launch(Wv, wqkv_bf + 4718592, 512 * 1024);
  cast_launch(Wo, wo_bf, 1024 * 2048);

  trig_kernel<<<(S_N * 32) / 256, 256, 0, stream>>>(pos, cost, sint);

  // QKV+gate projection: M=4096, N=5120, K=1024 -> qkv_raw bf16
  gemm_bt_kernel<1><<<32 * 40, 256, 0, stream>>>(hs_bf, wqkv_bf, (void*)qkv_raw, 4096, 5120, 1024);

  // RMSNorm + RoPE (q,k); V transpose
  normrope_kernel<<<(B_N * S_N * (H_N + HKV_N)) / 4, 256, 0, stream>>>(
      qkv_raw, qw, kw, cost, sint, q_r, k_r);
  vtrans_kernel<<<512, 256, 0, stream>>>(qkv_raw, vt);

  // attention + gating -> act bf16
  attn_kernel<<<B_N * H_N * (S_N / 64), 256, 0, stream>>>(q_r, k_r, vt, qkv_raw, act);

  // output projection: M=4096, N=1024, K=2048 -> d_out fp32
  gemm_bt_kernel<0><<<32 * 8, 256, 0, stream>>>(act, wo_bf, (void*)out, 4096, 1024, 2048);
}

// Round 2
// 256.429 us; speedup vs baseline: 1.1426x; 1.1426x over previous
//
#include <hip/hip_runtime.h>
#include <math.h>

typedef unsigned short u16;
typedef unsigned int   u32;
typedef __attribute__((ext_vector_type(4))) float f32x4;
typedef __attribute__((ext_vector_type(8))) short s16x8;
typedef __attribute__((ext_vector_type(4))) unsigned short u16x4;

#define B_N   2
#define S_N   2048
#define HID_N 1024
#define H_N   8
#define HKV_N 2
#define D_N   256
#define QKVW  5120   // qkv_raw row width: 2048 q | 2048 gate | 512 k | 512 v

__device__ __forceinline__ u16 f2bf(float f) {
  union { float f; u32 u; } x; x.f = f;
  u32 r = x.u + 0x7FFFu + ((x.u >> 16) & 1u);
  return (u16)(r >> 16);
}
__device__ __forceinline__ float bf2f(u16 u) {
  union { u32 u; float f; } x; x.u = ((u32)u) << 16; return x.f;
}
__device__ __forceinline__ void gload_lds16(const u16* g, u16* l) {
  __builtin_amdgcn_global_load_lds((const __attribute__((address_space(1))) u32*)g,
                                   (__attribute__((address_space(3))) u32*)l, 16, 0, 0);
}

// ---------------- fp32 -> bf16 cast ----------------
__global__ __launch_bounds__(256)
void cast_bf16_kernel(const float* __restrict__ src, u16* __restrict__ dst, int n4) {
  int i = blockIdx.x * blockDim.x + threadIdx.x;
  int stride = gridDim.x * blockDim.x;
  for (; i < n4; i += stride) {
    float4 v = reinterpret_cast<const float4*>(src)[i];
    u16x4 o;
    o.x = f2bf(v.x); o.y = f2bf(v.y); o.z = f2bf(v.z); o.w = f2bf(v.w);
    reinterpret_cast<u16x4*>(dst)[i] = o;
  }
}

// ---------------- RoPE trig table (fp64 on device, tiny) ----------------
__global__ __launch_bounds__(256)
void trig_kernel(const int* __restrict__ pos, float* __restrict__ ct, float* __restrict__ st) {
  int i = blockIdx.x * blockDim.x + threadIdx.x;
  if (i >= S_N * 32) return;
  int s = i >> 5, j = i & 31;
  double inv = exp(-(double)j * (log(1.0e7) / 32.0));
  double ang = (double)pos[s] * inv;
  ct[i] = (float)cos(ang);
  st[i] = (float)sin(ang);
}

// ---------------- bf16 GEMM: C[M,N] = A[M,K] @ Bw[N,K]^T ----------------
// 128x128 tile, BK=32, 4 waves (2x2), 16x16x32 MFMA, global_load_lds dbuf.
template <int OUT_BF16>
__global__ __launch_bounds__(256, 2)
void gemm_bt_kernel(const u16* __restrict__ A, const u16* __restrict__ Bw,
                    void* __restrict__ Cout, int M, int N, int K) {
  const int nbn = N >> 7;
  const int bm = blockIdx.x / nbn;
  const int bn = blockIdx.x % nbn;
  const int tid = threadIdx.x;
  const int lane = tid & 63;
  const int wr = tid >> 7;
  const int wc = (tid >> 6) & 1;
  __shared__ u16 sA[2][128 * 32];
  __shared__ u16 sB[2][128 * 32];
  f32x4 acc[4][4] = {};
  const u16* Ab = A + (size_t)(bm << 7) * K;
  const u16* Bb = Bw + (size_t)(bn << 7) * K;
  const int r_st = tid >> 2;
  const int c_st = (tid & 3) * 8;
  const int nkt = K >> 5;

  auto stage = [&](int buf, int kt) {
    const int k0 = kt << 5;
    gload_lds16(Ab + (size_t)r_st * K + k0 + c_st,        &sA[buf][tid * 8]);
    gload_lds16(Ab + (size_t)(r_st + 64) * K + k0 + c_st, &sA[buf][2048 + tid * 8]);
    gload_lds16(Bb + (size_t)r_st * K + k0 + c_st,        &sB[buf][tid * 8]);
    gload_lds16(Bb + (size_t)(r_st + 64) * K + k0 + c_st, &sB[buf][2048 + tid * 8]);
  };

  stage(0, 0);
  int cur = 0;
  const int ra = (wr << 6) + (lane & 15);
  const int rb = (wc << 6) + (lane & 15);
  const int ks = (lane >> 4) << 3;
  for (int kt = 0; kt < nkt; ++kt) {
    asm volatile("s_waitcnt vmcnt(0)" ::: "memory");
    __syncthreads();
    if (kt + 1 < nkt) stage(cur ^ 1, kt + 1);
    const u16* sa = sA[cur];
    const u16* sb = sB[cur];
    s16x8 af[4], bfr[4];
#pragma unroll
    for (int m = 0; m < 4; ++m) af[m] = *reinterpret_cast<const s16x8*>(sa + (ra + m * 16) * 32 + ks);
#pragma unroll
    for (int n = 0; n < 4; ++n) bfr[n] = *reinterpret_cast<const s16x8*>(sb + (rb + n * 16) * 32 + ks);
#pragma unroll
    for (int m = 0; m < 4; ++m)
#pragma unroll
      for (int n = 0; n < 4; ++n)
        acc[m][n] = __builtin_amdgcn_mfma_f32_16x16x32_bf16(af[m], bfr[n], acc[m][n], 0, 0, 0);
    cur ^= 1;
  }
  const int row0 = (bm << 7) + (wr << 6) + ((lane >> 4) << 2);
  const int col0 = (bn << 7) + (wc << 6) + (lane & 15);
#pragma unroll
  for (int m = 0; m < 4; ++m)
#pragma unroll
    for (int n = 0; n < 4; ++n)
#pragma unroll
      for (int j = 0; j < 4; ++j) {
        size_t idx = (size_t)(row0 + m * 16 + j) * N + col0 + n * 16;
        if (OUT_BF16) ((u16*)Cout)[idx] = f2bf(acc[m][n][j]);
        else          ((float*)Cout)[idx] = acc[m][n][j];
      }
}

// ---------------- RMSNorm + RoPE for q and k ----------------
__global__ __launch_bounds__(256)
void normrope_kernel(const u16* __restrict__ qkv, const float* __restrict__ qw,
                     const float* __restrict__ kw, const float* __restrict__ ct,
                     const float* __restrict__ st, u16* __restrict__ q_r,
                     u16* __restrict__ k_r) {
  const int lane = threadIdx.x & 63;
  const int row = blockIdx.x * 4 + (threadIdx.x >> 6);
  const int nq = B_N * S_N * H_N;
  const u16* src; u16* dst; const float* w;
  int s;
  if (row < nq) {
    int h = row & 7; int bs = row >> 3; s = bs & (S_N - 1); int b = bs >> 11;
    src = qkv + (size_t)(b * S_N + s) * QKVW + h * 256;
    dst = q_r + ((size_t)(b * H_N + h) * S_N + s) * 256;
    w = qw;
  } else {
    int r2 = row - nq;
    int h = r2 & 1; int bs = r2 >> 1; s = bs & (S_N - 1); int b = bs >> 11;
    src = qkv + (size_t)(b * S_N + s) * QKVW + 4096 + h * 256;
    dst = k_r + ((size_t)(b * HKV_N + h) * S_N + s) * 256;
    w = kw;
  }
  u16x4 xv = *reinterpret_cast<const u16x4*>(src + lane * 4);
  float x0 = bf2f(xv.x), x1 = bf2f(xv.y), x2 = bf2f(xv.z), x3 = bf2f(xv.w);
  float ss = x0 * x0 + x1 * x1 + x2 * x2 + x3 * x3;
#pragma unroll
  for (int off = 1; off < 64; off <<= 1) ss += __shfl_xor(ss, off);
  float rinv = rsqrtf(ss * (1.0f / 256.0f) + 1e-6f);
  float4 wv = *reinterpret_cast<const float4*>(w + lane * 4);
  float y[4] = { x0 * rinv * wv.x, x1 * rinv * wv.y, x2 * rinv * wv.z, x3 * rinv * wv.w };
  float p[4];
  p[0] = __shfl_xor(y[0], 8);
  p[1] = __shfl_xor(y[1], 8);
  p[2] = __shfl_xor(y[2], 8);
  p[3] = __shfl_xor(y[3], 8);
  if (lane < 16) {
    const float sgn = (lane < 8) ? -1.0f : 1.0f;
    const int jb = (lane * 4) & 31;
#pragma unroll
    for (int e = 0; e < 4; ++e) {
      float c = ct[(size_t)s * 32 + jb + e];
      float sn = st[(size_t)s * 32 + jb + e];
      y[e] = y[e] * c + sgn * p[e] * sn;
    }
  }
  u16x4 ov;
  ov.x = f2bf(y[0]); ov.y = f2bf(y[1]); ov.z = f2bf(y[2]); ov.w = f2bf(y[3]);
  *reinterpret_cast<u16x4*>(dst + lane * 4) = ov;
}

// ---------------- V transpose: qkv_raw v-part (b,s,kvh,d) -> vt[(b,kvh,d), s] ----------------
__global__ __launch_bounds__(256)
void vtrans_kernel(const u16* __restrict__ qkv, u16* __restrict__ vt) {
  const int bid = blockIdx.x;            // 4*32*4 = 512
  const int dt = bid & 3;
  const int stile = (bid >> 2) & 31;
  const int bh = bid >> 7;               // b*HKV+kvh
  const int b = bh >> 1, kvh = bh & 1;
  __shared__ u16 tile[64][68];
  const int t = threadIdx.x;
  const u16* src = qkv + (size_t)(b * S_N + stile * 64) * QKVW + 4608 + kvh * 256 + dt * 64;
#pragma unroll
  for (int i = 0; i < 2; ++i) {
    int sl = i * 32 + (t >> 3);
    int d8 = (t & 7) * 8;
    s16x8 v = *reinterpret_cast<const s16x8*>(src + (size_t)sl * QKVW + d8);
    u16x4 lo = { (u16)v[0], (u16)v[1], (u16)v[2], (u16)v[3] };
    u16x4 hi = { (u16)v[4], (u16)v[5], (u16)v[6], (u16)v[7] };
    *reinterpret_cast<u16x4*>(&tile[sl][d8]) = lo;
    *reinterpret_cast<u16x4*>(&tile[sl][d8 + 4]) = hi;
  }
  __syncthreads();
#pragma unroll
  for (int i = 0; i < 2; ++i) {
    int dl = i * 32 + (t >> 3);
    int s8 = (t & 7) * 8;
    u16 tmp[8];
#pragma unroll
    for (int e = 0; e < 8; ++e) tmp[e] = tile[s8 + e][dl];
    u16x4 lo = { tmp[0], tmp[1], tmp[2], tmp[3] };
    u16x4 hi = { tmp[4], tmp[5], tmp[6], tmp[7] };
    u16* dstp = vt + ((size_t)(bh * 256 + dt * 64 + dl)) * S_N + stile * 64 + s8;
    *reinterpret_cast<u16x4*>(dstp) = lo;
    *reinterpret_cast<u16x4*>(dstp + 4) = hi;
  }
}

// ---------------- flash attention + silu gating ----------------
// 8 waves (512 thr); wave owns 16 q rows (q-tile 128); KVBLK=64; D=256.
// K,V double-buffered in LDS (XOR-swizzled, pre-swizzled global source for
// global_load_lds); defer-rescale online softmax; XCD-swizzled blockIdx.
__global__ __launch_bounds__(512, 2)
void attn_kernel(const u16* __restrict__ q_r, const u16* __restrict__ k_r,
                 const u16* __restrict__ vt, const u16* __restrict__ qkv,
                 u16* __restrict__ act) {
  // XCD-aware remap: each XCD (blockIdx%8) works on a single (b,kvh) -> its
  // K/V working set (2MB) fits the 4MB per-XCD L2.
  const int dd = blockIdx.x;             // 0..255
  const int xcd = dd & 7;
  const int idx = dd >> 3;               // 0..31
  const int combo = xcd >> 1;            // b*2+kvh
  const int within = (xcd & 1) * 32 + idx;
  const int b = combo >> 1;
  const int kvh = combo & 1;
  const int h = kvh * 4 + (within >> 4);
  const int qt = within & 15;

  const int tid = threadIdx.x;
  const int lane = tid & 63;
  const int wv = tid >> 6;               // 0..7
  const int l15 = lane & 15;
  const int l4 = lane >> 4;

  __shared__ u16 sK[2][64 * 256];        // [kv][d], swizzled 16B slots
  __shared__ u16 sVt[2][256 * 64];       // [d][kv], swizzled
  __shared__ u16 sP[8][16 * 64];         // per-wave P tile, swizzled

  const int q0 = qt * 128 + wv * 16;
  const u16* qb = q_r + ((size_t)(b * H_N + h) * S_N + q0) * 256;
  s16x8 qf[8];
#pragma unroll
  for (int kk = 0; kk < 8; ++kk)
    qf[kk] = *reinterpret_cast<const s16x8*>(qb + (size_t)l15 * 256 + kk * 32 + l4 * 8);

  f32x4 oacc[16] = {};
  float mrow[4] = { -1e30f, -1e30f, -1e30f, -1e30f };
  float lrow[4] = { 0.f, 0.f, 0.f, 0.f };

  const u16* kbase = k_r + ((size_t)(b * HKV_N + kvh) * S_N) * 256;
  const u16* vbase = vt + ((size_t)(b * HKV_N + kvh) * 256) * S_N;

  const int krow_b = tid >> 5;           // 0..15
  const int kp = tid & 31;
  const int vrow_b = tid >> 3;           // 0..63
  const int vp = tid & 7;

  auto stageKV = [&](int buf, int step) {
    const int kv0 = step << 6;
#pragma unroll
    for (int i = 0; i < 4; ++i) {
      const int krow = i * 16 + krow_b;
      gload_lds16(kbase + (size_t)(kv0 + krow) * 256 + ((kp ^ (krow_b & 7)) << 3),
                  &sK[buf][i * 4096 + tid * 8]);
    }
#pragma unroll
    for (int i = 0; i < 4; ++i) {
      const int vrow = i * 64 + vrow_b;
      gload_lds16(vbase + (size_t)vrow * S_N + kv0 + ((vp ^ (vrow_b & 7)) << 3),
                  &sVt[buf][i * 4096 + tid * 8]);
    }
  };

  stageKV(0, 0);
  int cur = 0;
  const float scale = 0.0625f;  // 1/sqrt(256)
  const int sw = (l15 & 7);
  for (int step = 0; step < 32; ++step) {
    asm volatile("s_waitcnt vmcnt(0)" ::: "memory");
    __syncthreads();
    if (step + 1 < 32) stageKV(cur ^ 1, step + 1);
    const u16* ktile = sK[cur];
    const u16* vtile = sVt[cur];

    // QK^T: 64 kv cols in 4 groups of 16
    f32x4 sacc[4] = {};
#pragma unroll
    for (int kk = 0; kk < 8; ++kk) {
      const int slot = kk * 4 + l4;
#pragma unroll
      for (int g = 0; g < 4; ++g) {
        const int row = g * 16 + l15;
        s16x8 kf = *reinterpret_cast<const s16x8*>(ktile + row * 256 + ((slot ^ sw) << 3));
        sacc[g] = __builtin_amdgcn_mfma_f32_16x16x32_bf16(qf[kk], kf, sacc[g], 0, 0, 0);
      }
    }

    // online softmax with defer-rescale (exact, THR=0)
    float sc[16];
#pragma unroll
    for (int g = 0; g < 4; ++g)
#pragma unroll
      for (int j = 0; j < 4; ++j) sc[g * 4 + j] = sacc[g][j] * scale;
    float vmax[4];
#pragma unroll
    for (int j = 0; j < 4; ++j) {
      float v = fmaxf(fmaxf(sc[j], sc[4 + j]), fmaxf(sc[8 + j], sc[12 + j]));
      v = fmaxf(v, __shfl_xor(v, 1));
      v = fmaxf(v, __shfl_xor(v, 2));
      v = fmaxf(v, __shfl_xor(v, 4));
      v = fmaxf(v, __shfl_xor(v, 8));
      vmax[j] = v;
    }
    float grow = fmaxf(fmaxf(vmax[0] - mrow[0], vmax[1] - mrow[1]),
                       fmaxf(vmax[2] - mrow[2], vmax[3] - mrow[3]));
    if (__any(grow > 0.0f)) {
      float alpha[4];
#pragma unroll
      for (int j = 0; j < 4; ++j) {
        float mnew = fmaxf(mrow[j], vmax[j]);
        alpha[j] = __expf(mrow[j] - mnew);
        mrow[j] = mnew;
        lrow[j] *= alpha[j];
      }
#pragma unroll
      for (int nf = 0; nf < 16; ++nf) {
        oacc[nf][0] *= alpha[0]; oacc[nf][1] *= alpha[1];
        oacc[nf][2] *= alpha[2]; oacc[nf][3] *= alpha[3];
      }
    }
    float p[16];
#pragma unroll
    for (int g = 0; g < 4; ++g)
#pragma unroll
      for (int j = 0; j < 4; ++j) p[g * 4 + j] = __expf(sc[g * 4 + j] - mrow[j]);
#pragma unroll
    for (int j = 0; j < 4; ++j) {
      float r = (p[j] + p[4 + j]) + (p[8 + j] + p[12 + j]);
      r += __shfl_xor(r, 1);
      r += __shfl_xor(r, 2);
      r += __shfl_xor(r, 4);
      r += __shfl_xor(r, 8);
      lrow[j] += r;
    }

    // P -> bf16 -> per-wave LDS (swizzled [16][64])
    u16* pl = &sP[wv][0];
#pragma unroll
    for (int g = 0; g < 4; ++g)
#pragma unroll
      for (int j = 0; j < 4; ++j) {
        const int row = l4 * 4 + j;
        const int col = g * 16 + l15;
        pl[row * 64 + ((((col >> 3) ^ (row & 7)) << 3) | (col & 7))] = f2bf(p[g * 4 + j]);
      }
    asm volatile("s_waitcnt lgkmcnt(0)" ::: "memory");
    __builtin_amdgcn_sched_barrier(0);

    // PV: O[q][d] += P[q][kv] @ V[kv][d]
#pragma unroll
    for (int chunk = 0; chunk < 2; ++chunk) {
      s16x8 paf = *reinterpret_cast<const s16x8*>(
          pl + l15 * 64 + (((chunk * 4 + l4) ^ sw) << 3));
#pragma unroll
      for (int nf = 0; nf < 16; ++nf) {
        const int d = nf * 16 + l15;
        s16x8 vf = *reinterpret_cast<const s16x8*>(
            vtile + d * 64 + (((chunk * 4 + l4) ^ sw) << 3));
        oacc[nf] = __builtin_amdgcn_mfma_f32_16x16x32_bf16(paf, vf, oacc[nf], 0, 0, 0);
      }
    }
    cur ^= 1;
  }

  // epilogue: O/l, silu(gate), write activation for final GEMM
  float invl[4];
#pragma unroll
  for (int j = 0; j < 4; ++j) invl[j] = 1.0f / lrow[j];
#pragma unroll
  for (int nf = 0; nf < 16; ++nf) {
#pragma unroll
    for (int j = 0; j < 4; ++j) {
      const int srow = q0 + l4 * 4 + j;
      const int d = nf * 16 + l15;
      float o = oacc[nf][j] * invl[j];
      float g = bf2f(qkv[(size_t)(b * S_N + srow) * QKVW + 2048 + h * 256 + d]);
      float sg = g / (1.0f + __expf(-g));
      act[(size_t)(b * S_N + srow) * 2048 + h * 256 + d] = f2bf(o * sg);
    }
  }
}

extern "C" void kernel_launch(void* const* d_in, const int* in_sizes, int n_in,
                              void* d_out, int out_size, void* d_ws, size_t ws_size,
                              hipStream_t stream) {
  const float* hs  = (const float*)d_in[0];
  const int*   pos = (const int*)d_in[1];
  const float* Wq  = (const float*)d_in[2];
  const float* Wk  = (const float*)d_in[3];
  const float* Wv  = (const float*)d_in[4];
  const float* Wo  = (const float*)d_in[5];
  const float* qw  = (const float*)d_in[6];
  const float* kw  = (const float*)d_in[7];
  float* out = (float*)d_out;

  char* w8 = (char*)d_ws;
  u16* hs_bf   = (u16*)(w8);                    // 8,388,608 B
  u16* wqkv_bf = (u16*)(w8 + 8388608);          // 10,485,760
  u16* wo_bf   = (u16*)(w8 + 18874368);         // 4,194,304
  u16* qkv_raw = (u16*)(w8 + 23068672);         // 41,943,040
  u16* q_r     = (u16*)(w8 + 65011712);         // 16,777,216
  u16* k_r     = (u16*)(w8 + 81788928);         // 4,194,304
  u16* vt      = (u16*)(w8 + 85983232);         // 4,194,304
  u16* act     = (u16*)(w8 + 90177536);         // 16,777,216
  float* cost  = (float*)(w8 + 106954752);      // 262,144
  float* sint  = (float*)(w8 + 107216896);      // 262,144  -> total 107,479,040

  auto cast_launch = [&](const float* src, u16* dst, int n) {
    int n4 = n >> 2;
    int blocks = (n4 + 255) / 256;
    if (blocks > 2048) blocks = 2048;
    cast_bf16_kernel<<<blocks, 256, 0, stream>>>(src, dst, n4);
  };
  cast_launch(hs, hs_bf, B_N * S_N * HID_N);
  cast_launch(Wq, wqkv_bf, 4096 * 1024);
  cast_launch(Wk, wqkv_bf + 4194304, 512 * 1024);
  cast_launch(Wv, wqkv_bf + 4718592, 512 * 1024);
  cast_launch(Wo, wo_bf, 1024 * 2048);

  trig_kernel<<<(S_N * 32) / 256, 256, 0, stream>>>(pos, cost, sint);

  // QKV+gate projection: M=4096, N=5120, K=1024 -> qkv_raw bf16
  gemm_bt_kernel<1><<<32 * 40, 256, 0, stream>>>(hs_bf, wqkv_bf, (void*)qkv_raw, 4096, 5120, 1024);

  // RMSNorm + RoPE (q,k); V transpose
  normrope_kernel<<<(B_N * S_N * (H_N + HKV_N)) / 4, 256, 0, stream>>>(
      qkv_raw, qw, kw, cost, sint, q_r, k_r);
  vtrans_kernel<<<512, 256, 0, stream>>>(qkv_raw, vt);

  // attention + gating -> act bf16 (grid 256 = 1 block/CU, 8 waves)
  attn_kernel<<<256, 512, 0, stream>>>(q_r, k_r, vt, qkv_raw, act);

  // output projection: M=4096, N=1024, K=2048 -> d_out fp32
  gemm_bt_kernel<0><<<32 * 8, 256, 0, stream>>>(act, wo_bf, (void*)out, 4096, 1024, 2048);
}